// Round 1
// 778.021 us; speedup vs baseline: 1.0098x; 1.0098x over previous
//
#include <hip/hip_runtime.h>
#include <hip/hip_bf16.h>
#include <float.h>

// Problem: B=16, S=257, H=768, V=30522, P=32, topk=8 (fixed shapes).
#define BB 16
#define SS 257
#define SP 256      // S-1
#define HH 768
#define VV 30522
#define NF2 15261   // VV/2 (row is exactly NF2 float2's; row byte offset % 8 == 0)
#define NF4 7630    // float4 count of the 16B-aligned 30520-float region per row
#define PP 32
#define KK 8
#define CAP 2048    // candidate buffer; also holds 256*8 fallback entries

// ---------------------------------------------------------------------------
// Pass A (row-wise): per (b,s) row of 30522 logits compute
//   Z = sum(exp(x)) -> invZ   (no max-shift: inputs N(0,1), exp() safe)
//   top-8 of mask*log1p(relu(x)) -> expert_weights/ids (+ rm_seq scatter)
// v3: float4 loads. Row byte offset = rg*122088 ≡ 8*(rg&1) (mod 16), so the
// float4 region starts at float index ofs = 2*(rg&1); the 2 leftover floats
// are handled by thread 0. Candidate checks gated by wave-uniform __any
// (P(any candidate in a wave's 256 floats) ~= 0.29 at T=3.0).
// Also folds the W->Wt transpose into blocks 0..95 (96*256 == PP*HH).
// ---------------------------------------------------------------------------
__global__ __launch_bounds__(256) void rowstats_kernel(
    const float* __restrict__ logits, const float* __restrict__ amask,
    const float* __restrict__ W, float* __restrict__ Wt,
    float* __restrict__ invZ, float* __restrict__ o_rm,
    float* __restrict__ o_mask, float* __restrict__ o_ids,
    float* __restrict__ o_w)
{
  const int tid = threadIdx.x;
  const int row = blockIdx.x;          // 0..4095

  // Folded transw: Wt[k*PP+p] = W[p*HH+k]; ready before expertk launches.
  if (row < (PP * HH) / 256) {
    int i = row * 256 + tid;
    int p = i / HH, k = i - p * HH;
    Wt[k * PP + p] = W[i];
  }

  const int b = row >> 8, s = row & 255;
  const int rg = b * SS + s + 1;       // global logits row
  const float* lp = logits + (size_t)rg * VV;
  const float mval = amask[b * SS + s + 1];
  const bool mz = (mval != 0.0f);
  const int ofs = (rg & 1) ? 2 : 0;    // 16B-aligned float4 region starts here
  const float4* lp4 = (const float4*)(lp + ofs);

  __shared__ float cv[CAP];
  __shared__ int   ci[CAP];
  __shared__ float red[4];
  __shared__ int   cnt;
  if (tid == 0) cnt = 0;
  __syncthreads();

  const float T = 3.0f;
  float z0 = 0.0f, z1 = 0.0f, z2 = 0.0f, z3 = 0.0f;

  auto do4 = [&](float4 x, int fidx, float& za, float& zb) {
    za += __expf(x.x) + __expf(x.y);
    zb += __expf(x.z) + __expf(x.w);
    float m4 = fmaxf(fmaxf(x.x, x.y), fmaxf(x.z, x.w));
    if (__any(mz && (m4 > T))) {       // wave-uniform skip of the branchy path
      if (mz) {
        int v = ofs + 4 * fidx;
        if (x.x > T) { int p = atomicAdd(&cnt, 1); if (p < CAP) { cv[p] = x.x; ci[p] = v;     } }
        if (x.y > T) { int p = atomicAdd(&cnt, 1); if (p < CAP) { cv[p] = x.y; ci[p] = v + 1; } }
        if (x.z > T) { int p = atomicAdd(&cnt, 1); if (p < CAP) { cv[p] = x.z; ci[p] = v + 2; } }
        if (x.w > T) { int p = atomicAdd(&cnt, 1); if (p < CAP) { cv[p] = x.w; ci[p] = v + 3; } }
      }
    }
  };

  // NF4 = 7630 = 29*256 + 206: 7 batches of 4 strides + 1 stride + partial.
  for (int k = 0; k < 28; k += 4) {
    float4 x0 = lp4[tid + 256 * (k + 0)];
    float4 x1 = lp4[tid + 256 * (k + 1)];
    float4 x2 = lp4[tid + 256 * (k + 2)];
    float4 x3 = lp4[tid + 256 * (k + 3)];
    do4(x0, tid + 256 * (k + 0), z0, z1);
    do4(x1, tid + 256 * (k + 1), z2, z3);
    do4(x2, tid + 256 * (k + 2), z0, z1);
    do4(x3, tid + 256 * (k + 3), z2, z3);
  }
  {
    float4 x = lp4[tid + 256 * 28];
    do4(x, tid + 256 * 28, z0, z1);
  }
  {
    int f = tid + 256 * 29;
    if (f < NF4) {                     // 206 active lanes; __any over active ok
      float4 x = lp4[f];
      do4(x, f, z2, z3);
    }
  }
  // 2 leftover floats (row start if ofs==2, row end if ofs==0).
  if (tid == 0) {
    int l0 = ofs ? 0 : (NF4 * 4);
    #pragma unroll
    for (int j = 0; j < 2; ++j) {
      float x = lp[l0 + j];
      z0 += __expf(x);
      if (mz && x > T) { int p = atomicAdd(&cnt, 1); if (p < CAP) { cv[p] = x; ci[p] = l0 + j; } }
    }
  }

  float zsum = (z0 + z1) + (z2 + z3);
  #pragma unroll
  for (int off = 32; off; off >>= 1) zsum += __shfl_xor(zsum, off, 64);
  if ((tid & 63) == 0) red[tid >> 6] = zsum;
  __syncthreads();                     // also makes candidate appends visible
  if (tid == 0) invZ[row] = 1.0f / ((red[0] + red[1]) + (red[2] + red[3]));

  int n = cnt;                         // block-uniform after barrier
  if (n < KK || n > CAP) {
    // Exact fallback: per-thread sorted top-8 over clamped masked values.
    const float2* lp2 = (const float2*)lp;
    float lv[KK]; int li[KK];
    #pragma unroll
    for (int j = 0; j < KK; ++j) { lv[j] = -1.0f; li[j] = 0; }
    for (int c = tid; c < NF2; c += 256) {
      float2 x = lp2[c];
      float v0 = mz ? fmaxf(x.x, 0.0f) : 0.0f;
      float v1 = mz ? fmaxf(x.y, 0.0f) : 0.0f;
      if (v0 > lv[KK - 1]) {           // strict >: equal value keeps earlier index
        #pragma unroll
        for (int j = KK - 1; j >= 1; --j) {
          bool a = lv[j - 1] < v0;
          bool q = lv[j] < v0;
          lv[j] = a ? lv[j - 1] : (q ? v0 : lv[j]);
          li[j] = a ? li[j - 1] : (q ? (2 * c) : li[j]);
        }
        if (lv[0] < v0) { lv[0] = v0; li[0] = 2 * c; }
      }
      if (v1 > lv[KK - 1]) {
        #pragma unroll
        for (int j = KK - 1; j >= 1; --j) {
          bool a = lv[j - 1] < v1;
          bool q = lv[j] < v1;
          lv[j] = a ? lv[j - 1] : (q ? v1 : lv[j]);
          li[j] = a ? li[j - 1] : (q ? (2 * c + 1) : li[j]);
        }
        if (lv[0] < v1) { lv[0] = v1; li[0] = 2 * c + 1; }
      }
    }
    #pragma unroll
    for (int j = 0; j < KK; ++j) { cv[tid * KK + j] = lv[j]; ci[tid * KK + j] = li[j]; }
    n = CAP;
    __syncthreads();
  }

  // Barrier-free extraction: wave 0 only, shuffle-butterfly argmax × 8.
  // Tie-break = jax top_k (value desc, index asc).
  if (tid < 64) {
    #pragma unroll 1
    for (int kk = 0; kk < KK; ++kk) {
      float mv = -FLT_MAX; int mi = 0x7fffffff; int ms = -1;
      for (int j = tid; j < n; j += 64) {
        float v = cv[j]; int ix = ci[j];
        if (v > mv || (v == mv && ix < mi)) { mv = v; mi = ix; ms = j; }
      }
      #pragma unroll
      for (int off = 32; off; off >>= 1) {
        float ov = __shfl_xor(mv, off, 64);
        int   oi = __shfl_xor(mi, off, 64);
        int   os = __shfl_xor(ms, off, 64);
        if (ov > mv || (ov == mv && oi < mi)) { mv = ov; mi = oi; ms = os; }
      }
      if (tid == 0) cv[ms] = -FLT_MAX; // same-wave LDS: in-order, no barrier
      if (tid == kk) {
        float w = mval * log1pf(fmaxf(mv, 0.0f));
        o_w[(size_t)row * KK + kk] = w;
        o_ids[(size_t)row * KK + kk] = (float)mi;
        if (w > 0.0f) atomicAdd(&o_rm[(size_t)b * VV + mi], 1.0f);
      }
    }
  }
  if (tid == 0) o_mask[row] = mval;
}

// ---------------------------------------------------------------------------
// Pass B (column-wise): per (b, v) over s:
//   router_softmax_sum[b,v] = sum_s exp(x)*invZ[b,s]
//   router_repr[b,v]        = log1p(max_s (mask? relu(x):0))   (monotone fold)
// 4 independent s-streams per thread + unroll 2 → 8 loads in flight.
// v3: folds reducerm (avg_cond/avg_marg over o_rm) into flat blocks 0..119.
// ---------------------------------------------------------------------------
__global__ __launch_bounds__(256) void colstats_kernel(
    const float* __restrict__ logits, const float* __restrict__ amask,
    const float* __restrict__ invZ, const float* __restrict__ rm,
    float* __restrict__ o_rss, float* __restrict__ o_rrepr,
    float* __restrict__ out01)
{
  const int b = blockIdx.y;
  const int tid = threadIdx.x;
  const int c = blockIdx.x * 256 + tid;   // float2 column index
  __shared__ float zi[SP];
  __shared__ float mm[SP];
  zi[tid] = invZ[b * SP + tid];
  mm[tid] = amask[b * SS + 1 + tid];
  __syncthreads();
  if (c < NF2) {
    const float2* base = (const float2*)(logits + (size_t)(b * SS + 1) * VV) + c;
    float a0 = 0, a1 = 0, b0 = 0, b1 = 0, e0 = 0, e1 = 0, f0 = 0, f1 = 0;
    float g0 = 0, g1 = 0, h0 = 0, h1 = 0, i0 = 0, i1 = 0, j0 = 0, j1 = 0;
    #pragma unroll 2
    for (int s = 0; s < 64; ++s) {
      float2 x0 = base[(size_t)(s)       * NF2];
      float2 x1 = base[(size_t)(s +  64) * NF2];
      float2 x2 = base[(size_t)(s + 128) * NF2];
      float2 x3 = base[(size_t)(s + 192) * NF2];
      a0 = fmaf(__expf(x0.x), zi[s      ], a0);  a1 = fmaf(__expf(x0.y), zi[s      ], a1);
      b0 = fmaf(__expf(x1.x), zi[s +  64], b0);  b1 = fmaf(__expf(x1.y), zi[s +  64], b1);
      e0 = fmaf(__expf(x2.x), zi[s + 128], e0);  e1 = fmaf(__expf(x2.y), zi[s + 128], e1);
      f0 = fmaf(__expf(x3.x), zi[s + 192], f0);  f1 = fmaf(__expf(x3.y), zi[s + 192], f1);
      g0 = fmaxf(g0, mm[s      ] != 0.f ? x0.x : 0.f); g1 = fmaxf(g1, mm[s      ] != 0.f ? x0.y : 0.f);
      h0 = fmaxf(h0, mm[s +  64] != 0.f ? x1.x : 0.f); h1 = fmaxf(h1, mm[s +  64] != 0.f ? x1.y : 0.f);
      i0 = fmaxf(i0, mm[s + 128] != 0.f ? x2.x : 0.f); i1 = fmaxf(i1, mm[s + 128] != 0.f ? x2.y : 0.f);
      j0 = fmaxf(j0, mm[s + 192] != 0.f ? x3.x : 0.f); j1 = fmaxf(j1, mm[s + 192] != 0.f ? x3.y : 0.f);
    }
    float sa = (a0 + b0) + (e0 + f0);
    float sb = (a1 + b1) + (e1 + f1);
    float ma = fmaxf(fmaxf(g0, h0), fmaxf(i0, j0));
    float mb = fmaxf(fmaxf(g1, h1), fmaxf(i1, j1));
    size_t o = (size_t)b * VV + 2 * (size_t)c;
    *(float2*)(o_rss + o)   = make_float2(sa, sb);
    *(float2*)(o_rrepr + o) = make_float2(log1pf(ma), log1pf(mb));
  }

  // Folded reducerm: avg_cond = sum(rm)/B ; avg_marg = sum_v max_b rm[b,v].
  // rm (written by rowstats) is complete: same-stream ordering.
  const int fb = blockIdx.y * gridDim.x + blockIdx.x;   // 0..959
  if (fb < (VV + 255) / 256) {                          // 120 blocks
    int v = fb * 256 + tid;
    float sm = 0.0f, mx = 0.0f;
    if (v < VV) {
      #pragma unroll
      for (int b2 = 0; b2 < BB; ++b2) {
        float r = rm[(size_t)b2 * VV + v];
        sm += r; mx = fmaxf(mx, r);
      }
    }
    __shared__ float rs[256], rx[256];
    rs[tid] = sm; rx[tid] = mx;
    __syncthreads();
    #pragma unroll
    for (int st = 128; st > 0; st >>= 1) {
      if (tid < st) {
        rs[tid] += rs[tid + st];
        rx[tid] += rx[tid + st];
      }
      __syncthreads();
    }
    if (tid == 0) {
      atomicAdd(&out01[0], rs[0] * (1.0f / BB));
      atomicAdd(&out01[1], rx[0]);
    }
  }
}

// ---------------------------------------------------------------------------
// expert_repr[b,s,p] = (hiddens[b,s,:] . W_tok[p,:] + b_tok[p]) * mask[b,s]
// One block per (b,s) row; hidden row staged in LDS; Wt reads coalesced.
// ---------------------------------------------------------------------------
__global__ __launch_bounds__(256) void expertk_kernel(
    const float* __restrict__ hs, const float* __restrict__ amask,
    const float* __restrict__ Wt, const float* __restrict__ btok,
    float* __restrict__ o_er)
{
  const int row = blockIdx.x;
  const int b = row >> 8, s = row & 255;
  const float* hp = hs + (size_t)(b * SS + s + 1) * HH;
  __shared__ float h[HH];
  __shared__ float psum[8][PP];
  for (int i = threadIdx.x; i < HH; i += 256) h[i] = hp[i];
  __syncthreads();
  const int p = threadIdx.x & 31, g = threadIdx.x >> 5;
  float acc = 0.0f;
  #pragma unroll 8
  for (int k = g * 96; k < g * 96 + 96; ++k) acc = fmaf(h[k], Wt[k * PP + p], acc);
  psum[g][p] = acc;
  __syncthreads();
  if (threadIdx.x < PP) {
    float r = 0.0f;
    #pragma unroll
    for (int g2 = 0; g2 < 8; ++g2) r += psum[g2][threadIdx.x];
    float mval = amask[b * SS + s + 1];
    o_er[(size_t)row * PP + threadIdx.x] = (r + btok[threadIdx.x]) * mval;
  }
}

extern "C" void kernel_launch(void* const* d_in, const int* in_sizes, int n_in,
                              void* d_out, int out_size, void* d_ws, size_t ws_size,
                              hipStream_t stream) {
  const float* hs     = (const float*)d_in[0];  // (16,257,768)
  const float* logits = (const float*)d_in[1];  // (16,257,30522)
  const float* amask  = (const float*)d_in[2];  // (16,257)
  const float* W      = (const float*)d_in[3];  // (32,768)
  const float* btok   = (const float*)d_in[4];  // (32,)
  // d_in[5] = topk scalar (8), compile-time constant here.

  float* out    = (float*)d_out;
  float* o_cond = out;                                  // [0],[1]
  float* o_rm   = out + 2;                              // (16,30522)
  float* o_rss  = o_rm + (size_t)BB * VV;               // (16,30522)
  float* o_mask = o_rss + (size_t)BB * VV;              // (16,256)
  float* o_rrepr= o_mask + (size_t)BB * SP;             // (16,30522)
  float* o_ids  = o_rrepr + (size_t)BB * VV;            // (16,256,8) as float
  float* o_er   = o_ids + (size_t)BB * SP * KK;         // (16,256,32)
  float* o_w    = o_er + (size_t)BB * SP * PP;          // (16,256,8)

  float* wsf  = (float*)d_ws;
  float* invZ = wsf;            // 4096 floats
  float* Wt   = wsf + 4096;     // 24576 floats

  // zero avg_cond, avg_marg, rm_seq (contiguous prefix)
  hipMemsetAsync(out, 0, (2 + (size_t)BB * VV) * sizeof(float), stream);

  rowstats_kernel<<<BB * SP, 256, 0, stream>>>(logits, amask, W, Wt, invZ, o_rm, o_mask, o_ids, o_w);
  colstats_kernel<<<dim3((NF2 + 255) / 256, BB), 256, 0, stream>>>(logits, amask, invZ, o_rm, o_rss, o_rrepr, o_cond);
  expertk_kernel<<<BB * SP, 256, 0, stream>>>(hs, amask, Wt, btok, o_er);
}